// Round 1
// baseline (5055.407 us; speedup 1.0000x reference)
//
#include <hip/hip_runtime.h>

namespace {
constexpr int IMG    = 256;
constexpr int CIN    = 192;
constexpr int NHEADS = 6;
constexpr int HD     = 32;
constexpr int WA     = 64;    // tokens per 8x8 window
constexpr int NWIN   = 1024;  // windows per batch image (32x32)
constexpr float SCALE = 0.17677669529663687f;  // 32^-0.5
}

__global__ __launch_bounds__(256)
void wmsa_fused(const float* __restrict__ x,
                const float* __restrict__ w_qkv,
                const float* __restrict__ b_qkv,
                const float* __restrict__ rel_pos,
                const float* __restrict__ w_out,
                const float* __restrict__ b_out,
                float* __restrict__ out)
{
    // Padded so per-lane row strides are odd-ish mod 32 banks (2-way max = free).
    __shared__ float x_lds[WA][CIN + 1];              // 49.4 KB
    __shared__ float q_lds[WA][HD + 1];               //  8.45 KB (scaled q)
    __shared__ float k_lds[WA][HD + 1];               //  8.45 KB
    __shared__ __align__(16) float v_lds[WA][HD];     //  8 KB (rows 128B -> float4 ok)
    __shared__ float p_lds[WA][WA + 1];               // 16.6 KB
    __shared__ float rinv[WA];
    __shared__ float out_lds[WA][CIN + 1];            // 49.4 KB
    // total ~137.5 KB < 160 KB

    const int tid = threadIdx.x;
    const int b   = blockIdx.x >> 10;
    const int win = blockIdx.x & (NWIN - 1);
    const int wy  = win >> 5, wx = win & 31;

    // ---- load x window; roll(-4,-4) means token (ty,tx) of window (wy,wx)
    //      reads global pixel ((wy*8+ty+4)%256, (wx*8+tx+4)%256).
    //      (Identical address math applies to the final store: roll(+4) undoes it.)
    for (int i = tid; i < WA * (CIN / 4); i += 256) {
        const int t  = i / (CIN / 4);
        const int c4 = i % (CIN / 4);
        const int pr = ((wy << 3) + (t >> 3) + 4) & (IMG - 1);
        const int pc = ((wx << 3) + (t & 7) + 4) & (IMG - 1);
        const float4 v = *reinterpret_cast<const float4*>(
            x + (size_t)((b * IMG + pr) * IMG + pc) * CIN + c4 * 4);
        x_lds[t][c4 * 4 + 0] = v.x;
        x_lds[t][c4 * 4 + 1] = v.y;
        x_lds[t][c4 * 4 + 2] = v.z;
        x_lds[t][c4 * 4 + 3] = v.w;
    }
    __syncthreads();

    const int lt = tid & 63;   // token lane
    const int cg = tid >> 6;   // 0..3 column group

    for (int h = 0; h < NHEADS; ++h) {
        // ---- QKV projection for this head. col in 576 = which*192 + h*32 + d ----
        for (int which = 0; which < 3; ++which) {
            const int colbase = which * CIN + h * HD + cg * 8;
            float acc[8];
            #pragma unroll
            for (int j = 0; j < 8; ++j) acc[j] = b_qkv[colbase + j];
            for (int kk = 0; kk < CIN; ++kk) {
                const float xv = x_lds[lt][kk];
                const float4 w0 = *reinterpret_cast<const float4*>(w_qkv + kk * 576 + colbase);
                const float4 w1 = *reinterpret_cast<const float4*>(w_qkv + kk * 576 + colbase + 4);
                acc[0] += xv * w0.x; acc[1] += xv * w0.y;
                acc[2] += xv * w0.z; acc[3] += xv * w0.w;
                acc[4] += xv * w1.x; acc[5] += xv * w1.y;
                acc[6] += xv * w1.z; acc[7] += xv * w1.w;
            }
            if (which == 0) {
                #pragma unroll
                for (int j = 0; j < 8; ++j) q_lds[lt][cg * 8 + j] = acc[j] * SCALE;
            } else if (which == 1) {
                #pragma unroll
                for (int j = 0; j < 8; ++j) k_lds[lt][cg * 8 + j] = acc[j];
            } else {
                #pragma unroll
                for (int j = 0; j < 8; ++j) v_lds[lt][cg * 8 + j] = acc[j];
            }
        }
        __syncthreads();

        // ---- scores: thread owns key column k=lt; q = cg + 4*i sweeps rows ----
        {
            float krow[HD];
            #pragma unroll
            for (int d = 0; d < HD; ++d) krow[d] = k_lds[lt][d];
            const int ky = lt >> 3, kx = lt & 7;
            for (int i = 0; i < 16; ++i) {
                const int q = cg + 4 * i;
                float s = 0.f;
                #pragma unroll
                for (int d = 0; d < HD; ++d) s += q_lds[q][d] * krow[d];
                const int qy = q >> 3, qx = q & 7;
                s += rel_pos[h * 225 + (qy - ky + 7) * 15 + (qx - kx + 7)];
                // shifted-window mask: only the LAST window (index 1023) of each image
                if (win == NWIN - 1 && ((q < 4) != (lt < 4))) s = -1e30f;
                p_lds[q][lt] = s;
            }
        }
        __syncthreads();

        // ---- softmax per query row (serial; wave 0 only — baseline) ----
        if (tid < WA) {
            float m = -1e30f;
            for (int k2 = 0; k2 < WA; ++k2) m = fmaxf(m, p_lds[tid][k2]);
            float ssum = 0.f;
            for (int k2 = 0; k2 < WA; ++k2) {
                const float e = __expf(p_lds[tid][k2] - m);
                p_lds[tid][k2] = e;
                ssum += e;
            }
            rinv[tid] = 1.0f / ssum;
        }
        __syncthreads();

        // ---- PV: thread owns query row q=lt, d = cg*8..+7 ----
        {
            const int dbase = cg * 8;
            float acc[8] = {0.f, 0.f, 0.f, 0.f, 0.f, 0.f, 0.f, 0.f};
            for (int k2 = 0; k2 < WA; ++k2) {
                const float pv = p_lds[lt][k2];
                const float4 v0 = *reinterpret_cast<const float4*>(&v_lds[k2][dbase]);
                const float4 v1 = *reinterpret_cast<const float4*>(&v_lds[k2][dbase + 4]);
                acc[0] += pv * v0.x; acc[1] += pv * v0.y;
                acc[2] += pv * v0.z; acc[3] += pv * v0.w;
                acc[4] += pv * v1.x; acc[5] += pv * v1.y;
                acc[6] += pv * v1.z; acc[7] += pv * v1.w;
            }
            const float ri = rinv[lt];
            #pragma unroll
            for (int j = 0; j < 8; ++j) out_lds[lt][h * HD + dbase + j] = acc[j] * ri;
        }
        __syncthreads();
    }

    // ---- output projection + roll(+4,+4) store ----
    {
        const int colbase = cg * 48;
        float acc[48];
        #pragma unroll
        for (int j = 0; j < 48; ++j) acc[j] = b_out[colbase + j];
        for (int kk = 0; kk < CIN; ++kk) {
            const float ov = out_lds[lt][kk];
            #pragma unroll
            for (int j4 = 0; j4 < 12; ++j4) {
                const float4 w4 = *reinterpret_cast<const float4*>(
                    w_out + kk * CIN + colbase + j4 * 4);
                acc[j4 * 4 + 0] += ov * w4.x; acc[j4 * 4 + 1] += ov * w4.y;
                acc[j4 * 4 + 2] += ov * w4.z; acc[j4 * 4 + 3] += ov * w4.w;
            }
        }
        const int pr = ((wy << 3) + (lt >> 3) + 4) & (IMG - 1);
        const int pc = ((wx << 3) + (lt & 7) + 4) & (IMG - 1);
        float* op = out + (size_t)((b * IMG + pr) * IMG + pc) * CIN + colbase;
        #pragma unroll
        for (int j4 = 0; j4 < 12; ++j4) {
            *reinterpret_cast<float4*>(op + j4 * 4) =
                make_float4(acc[j4 * 4], acc[j4 * 4 + 1], acc[j4 * 4 + 2], acc[j4 * 4 + 3]);
        }
    }
}

extern "C" void kernel_launch(void* const* d_in, const int* in_sizes, int n_in,
                              void* d_out, int out_size, void* d_ws, size_t ws_size,
                              hipStream_t stream)
{
    const float* x       = (const float*)d_in[0];
    const float* w_qkv   = (const float*)d_in[1];
    const float* b_qkv   = (const float*)d_in[2];
    const float* rel_pos = (const float*)d_in[3];
    const float* w_out   = (const float*)d_in[4];
    const float* b_out   = (const float*)d_in[5];
    float* out = (float*)d_out;

    wmsa_fused<<<dim3(4 * NWIN), dim3(256), 0, stream>>>(
        x, w_qkv, b_qkv, rel_pos, w_out, b_out, out);
}

// Round 2
// 739.875 us; speedup vs baseline: 6.8328x; 6.8328x over previous
//
#include <hip/hip_runtime.h>

typedef __attribute__((ext_vector_type(8))) short short8;
typedef __attribute__((ext_vector_type(4))) float f32x4;

#define MFMA(a, b, c) __builtin_amdgcn_mfma_f32_16x16x32_bf16((a), (b), (c), 0, 0, 0)

namespace {
constexpr int IMG = 256;
constexpr int NWIN = 1024;          // 32x32 windows per image
constexpr float SCALE = 0.17677669529663687f;  // 32^-0.5
}

__device__ __forceinline__ unsigned short f2bf(float f) {
    union { float f; unsigned u; } v; v.f = f;
    unsigned r = (v.u + 0x7FFFu + ((v.u >> 16) & 1u)) >> 16;
    return (unsigned short)r;
}
__device__ __forceinline__ unsigned pack2(float a, float b) {
    return (unsigned)f2bf(a) | ((unsigned)f2bf(b) << 16);
}

// fp32 [K][N] -> bf16 [N][K] (so MFMA A/B frags read 8 contiguous K elements)
__global__ __launch_bounds__(256) void to_bf16_T(const float* __restrict__ in,
                                                 unsigned short* __restrict__ out,
                                                 int K, int N) {
    __shared__ float tile[32][65];
    const int t = threadIdx.x;
    const int nb = blockIdx.x * 64, kb = blockIdx.y * 32;
    const int tn = t & 63, tk = t >> 6;
#pragma unroll
    for (int p = 0; p < 8; ++p)
        tile[p * 4 + tk][tn] = in[(size_t)(kb + p * 4 + tk) * N + nb + tn];
    __syncthreads();
    const int n = t >> 2, kc = (t & 3) * 8;
    uint4 u;
    u.x = pack2(tile[kc + 0][n], tile[kc + 1][n]);
    u.y = pack2(tile[kc + 2][n], tile[kc + 3][n]);
    u.z = pack2(tile[kc + 4][n], tile[kc + 5][n]);
    u.w = pack2(tile[kc + 6][n], tile[kc + 7][n]);
    *(uint4*)(out + (size_t)(nb + n) * K + kb + kc) = u;
}

__global__ __launch_bounds__(256, 2)
void wmsa_main(const float* __restrict__ x,
               const float* __restrict__ b_qkv,
               const float* __restrict__ rel_pos,
               const float* __restrict__ b_out,
               const unsigned short* __restrict__ wqT,   // bf16 [576][192]
               const unsigned short* __restrict__ woT,   // bf16 [192][192]
               float* __restrict__ out) {
    extern __shared__ unsigned short smem[];
    unsigned short (*x_s)[200]  = (unsigned short(*)[200]) smem;            // 64x200
    unsigned short (*ao_s)[200] = (unsigned short(*)[200])(smem + 12800);   // 64x200
    unsigned short (*q_s)[40]   = (unsigned short(*)[40]) (smem + 25600);   // 64x40 [tok][d]
    unsigned short (*k_s)[40]   = (unsigned short(*)[40]) (smem + 28160);   // 64x40 [tok][d]
    unsigned short (*vT_s)[72]  = (unsigned short(*)[72]) (smem + 30720);   // 32x72 [d][tok]
    unsigned short (*p_s)[72]   = (unsigned short(*)[72]) (smem + 33024);   // 64x72 [q][k]
    // total 37632 halfwords = 75264 B -> 2 blocks/CU

    const int tid = threadIdx.x;
    const int w   = tid >> 6;        // wave 0..3
    const int l   = tid & 63;
    const int l15 = l & 15, lg = l >> 4;
    const int b   = blockIdx.x >> 10;
    const int win = blockIdx.x & (NWIN - 1);
    const int wy  = win >> 5, wx = win & 31;
    const bool lastwin = (win == NWIN - 1);
    const f32x4 z = {0.f, 0.f, 0.f, 0.f};

    // ---- load x window (roll(-4,-4)) -> bf16 LDS [tok][c] ----
    for (int i = tid; i < 64 * 48; i += 256) {
        const int t = i / 48, c4 = i % 48;
        const int pr = ((wy << 3) + (t >> 3) + 4) & (IMG - 1);
        const int pc = ((wx << 3) + (t & 7) + 4) & (IMG - 1);
        const float4 xv = *reinterpret_cast<const float4*>(
            x + ((size_t)((b * IMG + pr) * IMG + pc)) * 192 + c4 * 4);
        uint2 pk; pk.x = pack2(xv.x, xv.y); pk.y = pack2(xv.z, xv.w);
        *(uint2*)(&x_s[t][c4 * 4]) = pk;
    }
    __syncthreads();

    const int tok_me = 16 * w + l15;   // this wave's token column

#pragma unroll 1
    for (int h = 0; h < 6; ++h) {
        const int arowq = h * 32, arowk = 192 + h * 32, arowv = 384 + h * 32;

        // ==== phase 1: QKV GEMMs ====
        // qk transposed GEMM: D[qkcol][tok], wave w = token N-tile w
        // v normal GEMM:      D[tok][vcol], wave w = token M-tile w
        f32x4 aqk[4] = {z, z, z, z};
        f32x4 av[2]  = {z, z};
#pragma unroll
        for (int ks = 0; ks < 6; ++ks) {
            const short8 xf = *(const short8*)(&x_s[tok_me][ks * 32 + lg * 8]);
#pragma unroll
            for (int mt = 0; mt < 4; ++mt) {
                const int ar = (mt < 2 ? arowq + 16 * mt : arowk + 16 * (mt - 2)) + l15;
                const short8 wf = *(const short8*)(wqT + (size_t)ar * 192 + ks * 32 + lg * 8);
                aqk[mt] = MFMA(wf, xf, aqk[mt]);
            }
#pragma unroll
            for (int nt = 0; nt < 2; ++nt) {
                const short8 wf = *(const short8*)(wqT + (size_t)(arowv + 16 * nt + l15) * 192 + ks * 32 + lg * 8);
                av[nt] = MFMA(xf, wf, av[nt]);
            }
        }
        // epilogue qk: lane holds col=tok_me, rows = qkcol 4*lg+j (per M-tile)
#pragma unroll
        for (int mt = 0; mt < 4; ++mt) {
            const int rbase = 4 * lg;
            const int colabs = (mt < 2 ? arowq + 16 * mt : arowk + 16 * (mt - 2)) + rbase;
            float v0 = aqk[mt][0] + b_qkv[colabs + 0];
            float v1 = aqk[mt][1] + b_qkv[colabs + 1];
            float v2 = aqk[mt][2] + b_qkv[colabs + 2];
            float v3 = aqk[mt][3] + b_qkv[colabs + 3];
            uint2 pk;
            if (mt < 2) {
                v0 *= SCALE; v1 *= SCALE; v2 *= SCALE; v3 *= SCALE;
                pk.x = pack2(v0, v1); pk.y = pack2(v2, v3);
                *(uint2*)(&q_s[tok_me][16 * mt + rbase]) = pk;
            } else {
                pk.x = pack2(v0, v1); pk.y = pack2(v2, v3);
                *(uint2*)(&k_s[tok_me][16 * (mt - 2) + rbase]) = pk;
            }
        }
        // epilogue v: lane holds col=vcol=16nt+l15, rows = toks 16w+4lg+j
#pragma unroll
        for (int nt = 0; nt < 2; ++nt) {
            const int d = 16 * nt + l15;
            const float bb = b_qkv[arowv + d];
            uint2 pk;
            pk.x = pack2(av[nt][0] + bb, av[nt][1] + bb);
            pk.y = pack2(av[nt][2] + bb, av[nt][3] + bb);
            *(uint2*)(&vT_s[d][16 * w + 4 * lg]) = pk;
        }
        __syncthreads();

        // ==== phase 2: S = q k^T (wave w = q-row tile w), softmax in regs ====
        const short8 qf = *(const short8*)(&q_s[tok_me][lg * 8]);
        f32x4 s[4];
#pragma unroll
        for (int nt = 0; nt < 4; ++nt) {
            const short8 kf = *(const short8*)(&k_s[16 * nt + l15][lg * 8]);
            s[nt] = MFMA(qf, kf, z);
        }
#pragma unroll
        for (int j = 0; j < 4; ++j) {
            const int q = 16 * w + 4 * lg + j;
            const int qy = q >> 3, qx = q & 7;
            float sv[4];
            float m = -1e30f;
#pragma unroll
            for (int nt = 0; nt < 4; ++nt) {
                const int kk = 16 * nt + l15;
                const int ky = kk >> 3, kx = kk & 7;
                float val = s[nt][j] + rel_pos[h * 225 + (qy - ky + 7) * 15 + (qx - kx + 7)];
                if (lastwin && ((q < 4) != (kk < 4))) val = -1e30f;
                sv[nt] = val;
                m = fmaxf(m, val);
            }
            m = fmaxf(m, __shfl_xor(m, 1));
            m = fmaxf(m, __shfl_xor(m, 2));
            m = fmaxf(m, __shfl_xor(m, 4));
            m = fmaxf(m, __shfl_xor(m, 8));
            float e[4], sum = 0.f;
#pragma unroll
            for (int nt = 0; nt < 4; ++nt) { e[nt] = __expf(sv[nt] - m); sum += e[nt]; }
            sum += __shfl_xor(sum, 1);
            sum += __shfl_xor(sum, 2);
            sum += __shfl_xor(sum, 4);
            sum += __shfl_xor(sum, 8);
            const float ri = __builtin_amdgcn_rcpf(sum);
#pragma unroll
            for (int nt = 0; nt < 4; ++nt)
                p_s[q][16 * nt + l15] = f2bf(e[nt] * ri);
        }
        __syncthreads();

        // ==== phase 3: O^T = V^T P^T  (wave w = q N-tile w) ====
        f32x4 o[2] = {z, z};
#pragma unroll
        for (int ksv = 0; ksv < 2; ++ksv) {
            const short8 pf = *(const short8*)(&p_s[tok_me][ksv * 32 + lg * 8]);
#pragma unroll
            for (int mt = 0; mt < 2; ++mt) {
                const short8 vf = *(const short8*)(&vT_s[16 * mt + l15][ksv * 32 + lg * 8]);
                o[mt] = MFMA(vf, pf, o[mt]);
            }
        }
#pragma unroll
        for (int mt = 0; mt < 2; ++mt) {
            const int dbase = 16 * mt + 4 * lg;
            uint2 pk;
            pk.x = pack2(o[mt][0], o[mt][1]);
            pk.y = pack2(o[mt][2], o[mt][3]);
            *(uint2*)(&ao_s[tok_me][h * 32 + dbase]) = pk;
        }
        __syncthreads();
    }

    // ==== phase 4: out = ao @ w_out + b_out, store with roll(+4,+4) ====
    f32x4 g[3][4];
#pragma unroll
    for (int ni = 0; ni < 3; ++ni)
#pragma unroll
        for (int mt = 0; mt < 4; ++mt) g[ni][mt] = z;

#pragma unroll
    for (int ks = 0; ks < 6; ++ks) {
        short8 af[4];
#pragma unroll
        for (int mt = 0; mt < 4; ++mt)
            af[mt] = *(const short8*)(&ao_s[16 * mt + l15][ks * 32 + lg * 8]);
#pragma unroll
        for (int ni = 0; ni < 3; ++ni) {
            const int nt = w + 4 * ni;
            const short8 bf = *(const short8*)(woT + (size_t)(16 * nt + l15) * 192 + ks * 32 + lg * 8);
#pragma unroll
            for (int mt = 0; mt < 4; ++mt) g[ni][mt] = MFMA(af[mt], bf, g[ni][mt]);
        }
    }
#pragma unroll
    for (int ni = 0; ni < 3; ++ni) {
        const int col = 16 * (w + 4 * ni) + l15;
        const float bo = b_out[col];
#pragma unroll
        for (int mt = 0; mt < 4; ++mt) {
#pragma unroll
            for (int j = 0; j < 4; ++j) {
                const int tok = 16 * mt + 4 * lg + j;
                const int pr = ((wy << 3) + (tok >> 3) + 4) & (IMG - 1);
                const int pc = ((wx << 3) + (tok & 7) + 4) & (IMG - 1);
                out[((size_t)((b * IMG + pr) * IMG + pc)) * 192 + col] = g[ni][mt][j] + bo;
            }
        }
    }
}

extern "C" void kernel_launch(void* const* d_in, const int* in_sizes, int n_in,
                              void* d_out, int out_size, void* d_ws, size_t ws_size,
                              hipStream_t stream) {
    (void)in_sizes; (void)n_in; (void)out_size; (void)ws_size;
    const float* x       = (const float*)d_in[0];
    const float* w_qkv   = (const float*)d_in[1];
    const float* b_qkv   = (const float*)d_in[2];
    const float* rel_pos = (const float*)d_in[3];
    const float* w_out   = (const float*)d_in[4];
    const float* b_out   = (const float*)d_in[5];
    float* out = (float*)d_out;

    unsigned short* wqT = (unsigned short*)d_ws;           // 576*192 bf16
    unsigned short* woT = wqT + 576 * 192;                 // 192*192 bf16  (needs 294912 B of ws)

    to_bf16_T<<<dim3(9, 6), 256, 0, stream>>>(w_qkv, wqT, 192, 576);
    to_bf16_T<<<dim3(3, 6), 256, 0, stream>>>(w_out, woT, 192, 192);

    wmsa_main<<<dim3(4 * NWIN), dim3(256), 75264, stream>>>(
        x, b_qkv, rel_pos, b_out, wqT, woT, out);
}

// Round 3
// 591.571 us; speedup vs baseline: 8.5457x; 1.2507x over previous
//
#include <hip/hip_runtime.h>

typedef __attribute__((ext_vector_type(8))) short short8;
typedef __attribute__((ext_vector_type(4))) float f32x4;
typedef __attribute__((ext_vector_type(4))) unsigned short u16x4;

#define MFMA(a, b, c) __builtin_amdgcn_mfma_f32_16x16x32_bf16((a), (b), (c), 0, 0, 0)

namespace {
constexpr int IMG = 256;
constexpr int NWIN = 1024;
constexpr float SCALE = 0.17677669529663687f;  // 32^-0.5
}

__device__ __forceinline__ unsigned short f2bf(float f) {
    union { float f; unsigned u; } v; v.f = f;
    return (unsigned short)((v.u + 0x7FFFu + ((v.u >> 16) & 1u)) >> 16);
}
__device__ __forceinline__ float bf2f(unsigned short h) {
    union { unsigned u; float f; } v; v.u = ((unsigned)h) << 16;
    return v.f;
}
__device__ __forceinline__ unsigned pack2(float a, float b) {
    return (unsigned)f2bf(a) | ((unsigned)f2bf(b) << 16);
}

// fp32 [K][N] -> bf16 [N][K]
__global__ __launch_bounds__(256) void to_bf16_T(const float* __restrict__ in,
                                                 unsigned short* __restrict__ out,
                                                 int K, int N) {
    __shared__ float tile[32][65];
    const int t = threadIdx.x;
    const int nb = blockIdx.x * 64, kb = blockIdx.y * 32;
    const int tn = t & 63, tk = t >> 6;
#pragma unroll
    for (int p = 0; p < 8; ++p)
        tile[p * 4 + tk][tn] = in[(size_t)(kb + p * 4 + tk) * N + nb + tn];
    __syncthreads();
    const int n = t >> 2, kc = (t & 3) * 8;
    uint4 u;
    u.x = pack2(tile[kc + 0][n], tile[kc + 1][n]);
    u.y = pack2(tile[kc + 2][n], tile[kc + 3][n]);
    u.z = pack2(tile[kc + 4][n], tile[kc + 5][n]);
    u.w = pack2(tile[kc + 6][n], tile[kc + 7][n]);
    *(uint4*)(out + (size_t)(nb + n) * K + kb + kc) = u;
}

// bias2[((h*64+q)*16 + l15)*4 + nt] = rel_pos bias for (q, k=16*nt+l15), bf16
__global__ __launch_bounds__(256) void build_bias(const float* __restrict__ rel_pos,
                                                  unsigned short* __restrict__ bias2) {
    const int o = blockIdx.x * 256 + threadIdx.x;   // 0..24575
    const int nt = o & 3, l15 = (o >> 2) & 15, q = (o >> 6) & 63, h = o >> 12;
    const int k = 16 * nt + l15;
    const int qy = q >> 3, qx = q & 7, ky = k >> 3, kx = k & 7;
    bias2[o] = f2bf(rel_pos[h * 225 + (qy - ky + 7) * 15 + (qx - kx + 7)]);
}

__global__ __launch_bounds__(256, 3)
void wmsa_main(const float* __restrict__ x,
               const float* __restrict__ b_qkv,
               const unsigned short* __restrict__ bias2,
               const float* __restrict__ b_out,
               const unsigned short* __restrict__ wqT,   // bf16 [576][192]
               const unsigned short* __restrict__ woT,   // bf16 [192][192]
               float* __restrict__ out) {
    __shared__ unsigned short q_s[64][40];    // [tok][d]      5.0 KB
    __shared__ unsigned short k_s[64][40];    // [tok][d]      5.0 KB
    __shared__ unsigned short vT_s[32][72];   // [d][tok]      4.5 KB
    __shared__ unsigned short p_s[64][72];    // [q][k]        9.0 KB
    __shared__ unsigned short ao_s[64][196];  // [tok][c]     24.5 KB
    // total 48 KB -> 3 blocks/CU

    const int tid = threadIdx.x;
    const int w   = tid >> 6;
    const int l   = tid & 63;
    const int l15 = l & 15, lg = l >> 4;
    const int b   = blockIdx.x >> 10;
    const int win = blockIdx.x & (NWIN - 1);
    const int wy  = win >> 5, wx = win & 31;
    const bool lastwin = (win == NWIN - 1);
    const f32x4 z = {0.f, 0.f, 0.f, 0.f};

    const int tok = 16 * w + l15;            // this lane's token (row/col in frags)
    const int pr  = ((wy << 3) + (tok >> 3) + 4) & (IMG - 1);
    const int pc  = ((wx << 3) + (tok & 7) + 4) & (IMG - 1);
    const float* xrow = x + (size_t)((b * IMG + pr) * IMG + pc) * 192;

    // ---- x window -> registers (roll(-4,-4) folded into pr/pc) ----
    short8 xf[6];
#pragma unroll
    for (int ks = 0; ks < 6; ++ks) {
        const int c0 = ks * 32 + lg * 8;
        const float4 a  = *reinterpret_cast<const float4*>(xrow + c0);
        const float4 b2 = *reinterpret_cast<const float4*>(xrow + c0 + 4);
        union { short8 s; unsigned u[4]; } pk;
        pk.u[0] = pack2(a.x, a.y);  pk.u[1] = pack2(a.z, a.w);
        pk.u[2] = pack2(b2.x, b2.y); pk.u[3] = pack2(b2.z, b2.w);
        xf[ks] = pk.s;
    }

#pragma unroll 1
    for (int h = 0; h < 6; ++h) {
        const int arowq = h * 32, arowk = 192 + h * 32, arowv = 384 + h * 32;

        // ==== phase 1: QKV GEMMs (x from regs) ====
        f32x4 aqk[4] = {z, z, z, z};
        f32x4 av[2]  = {z, z};
#pragma unroll
        for (int ks = 0; ks < 6; ++ks) {
            const int coff = ks * 32 + lg * 8;
#pragma unroll
            for (int mt = 0; mt < 4; ++mt) {
                const int ar = (mt < 2 ? arowq + 16 * mt : arowk + 16 * (mt - 2)) + l15;
                const short8 wf = *(const short8*)(wqT + (size_t)ar * 192 + coff);
                aqk[mt] = MFMA(wf, xf[ks], aqk[mt]);
            }
#pragma unroll
            for (int nt = 0; nt < 2; ++nt) {
                const short8 wf = *(const short8*)(wqT + (size_t)(arowv + 16 * nt + l15) * 192 + coff);
                av[nt] = MFMA(xf[ks], wf, av[nt]);
            }
        }
#pragma unroll
        for (int mt = 0; mt < 4; ++mt) {
            const int rbase = 4 * lg;
            const int colabs = (mt < 2 ? arowq + 16 * mt : arowk + 16 * (mt - 2)) + rbase;
            float v0 = aqk[mt][0] + b_qkv[colabs + 0];
            float v1 = aqk[mt][1] + b_qkv[colabs + 1];
            float v2 = aqk[mt][2] + b_qkv[colabs + 2];
            float v3 = aqk[mt][3] + b_qkv[colabs + 3];
            uint2 pk;
            if (mt < 2) {
                v0 *= SCALE; v1 *= SCALE; v2 *= SCALE; v3 *= SCALE;
                pk.x = pack2(v0, v1); pk.y = pack2(v2, v3);
                *(uint2*)(&q_s[tok][16 * mt + rbase]) = pk;
            } else {
                pk.x = pack2(v0, v1); pk.y = pack2(v2, v3);
                *(uint2*)(&k_s[tok][16 * (mt - 2) + rbase]) = pk;
            }
        }
#pragma unroll
        for (int nt = 0; nt < 2; ++nt) {
            const int d = 16 * nt + l15;
            const float bb = b_qkv[arowv + d];
            uint2 pk;
            pk.x = pack2(av[nt][0] + bb, av[nt][1] + bb);
            pk.y = pack2(av[nt][2] + bb, av[nt][3] + bb);
            *(uint2*)(&vT_s[d][16 * w + 4 * lg]) = pk;
        }
        __syncthreads();

        // ==== phase 2: S = q k^T, softmax (no max-sub; values bounded) ====
        u16x4 bb[4];
#pragma unroll
        for (int j = 0; j < 4; ++j) {
            const int q = 16 * w + 4 * lg + j;
            bb[j] = *(const u16x4*)(bias2 + (((h * 64 + q) * 16 + l15) << 2));
        }
        const short8 qf = *(const short8*)(&q_s[tok][lg * 8]);
        f32x4 s[4];
#pragma unroll
        for (int nt = 0; nt < 4; ++nt) {
            const short8 kf = *(const short8*)(&k_s[16 * nt + l15][lg * 8]);
            s[nt] = MFMA(qf, kf, z);
        }
#pragma unroll
        for (int j = 0; j < 4; ++j) {
            const int q = 16 * w + 4 * lg + j;
            float e[4], sum = 0.f;
#pragma unroll
            for (int nt = 0; nt < 4; ++nt) {
                float ee = __expf(s[nt][j] + bf2f(bb[j][nt]));
                if (lastwin && ((q < 4) != ((16 * nt + l15) < 4))) ee = 0.f;
                e[nt] = ee; sum += ee;
            }
            sum += __shfl_xor(sum, 1);
            sum += __shfl_xor(sum, 2);
            sum += __shfl_xor(sum, 4);
            sum += __shfl_xor(sum, 8);
            const float ri = __builtin_amdgcn_rcpf(sum);
#pragma unroll
            for (int nt = 0; nt < 4; ++nt)
                p_s[q][16 * nt + l15] = f2bf(e[nt] * ri);
        }
        __syncthreads();

        // ==== phase 3: O^T = V^T P^T ====
        f32x4 o[2] = {z, z};
#pragma unroll
        for (int ksv = 0; ksv < 2; ++ksv) {
            const short8 pf = *(const short8*)(&p_s[tok][ksv * 32 + lg * 8]);
#pragma unroll
            for (int mt = 0; mt < 2; ++mt) {
                const short8 vf = *(const short8*)(&vT_s[16 * mt + l15][ksv * 32 + lg * 8]);
                o[mt] = MFMA(vf, pf, o[mt]);
            }
        }
#pragma unroll
        for (int mt = 0; mt < 2; ++mt) {
            const int dbase = 16 * mt + 4 * lg;
            uint2 pk;
            pk.x = pack2(o[mt][0], o[mt][1]);
            pk.y = pack2(o[mt][2], o[mt][3]);
            *(uint2*)(&ao_s[tok][h * 32 + dbase]) = pk;
        }
        if (h < 5) __syncthreads();   // protect q/k/vT/p before next head's writes
    }
    // no barrier needed: GEMM2 reads only ao_s rows written by this same wave,
    // and intra-wave DS ops are processed in order.

    // ==== phase 4 (transposed): out^T[oc][tok] = woT[oc][:] . ao[tok][:] ====
    f32x4 g[12];
#pragma unroll
    for (int mt = 0; mt < 12; ++mt) g[mt] = z;
#pragma unroll
    for (int ks = 0; ks < 6; ++ks) {
        const int coff = ks * 32 + lg * 8;
        const short8 bfr = *(const short8*)(&ao_s[tok][coff]);
#pragma unroll
        for (int mt = 0; mt < 12; ++mt) {
            const short8 af = *(const short8*)(woT + (size_t)(16 * mt + l15) * 192 + coff);
            g[mt] = MFMA(af, bfr, g[mt]);
        }
    }
    float* orow = out + (size_t)((b * IMG + pr) * IMG + pc) * 192;  // same pixel as x (roll undone)
#pragma unroll
    for (int mt = 0; mt < 12; ++mt) {
        const int oc0 = 16 * mt + 4 * lg;
        const float4 bo = *reinterpret_cast<const float4*>(b_out + oc0);
        float4 vv;
        vv.x = g[mt][0] + bo.x; vv.y = g[mt][1] + bo.y;
        vv.z = g[mt][2] + bo.z; vv.w = g[mt][3] + bo.w;
        *reinterpret_cast<float4*>(orow + oc0) = vv;
    }
}

extern "C" void kernel_launch(void* const* d_in, const int* in_sizes, int n_in,
                              void* d_out, int out_size, void* d_ws, size_t ws_size,
                              hipStream_t stream) {
    (void)in_sizes; (void)n_in; (void)out_size; (void)ws_size;
    const float* x       = (const float*)d_in[0];
    const float* w_qkv   = (const float*)d_in[1];
    const float* b_qkv   = (const float*)d_in[2];
    const float* rel_pos = (const float*)d_in[3];
    const float* w_out   = (const float*)d_in[4];
    const float* b_out   = (const float*)d_in[5];
    float* out = (float*)d_out;

    unsigned short* wqT   = (unsigned short*)d_ws;       // 576*192 bf16 = 221184 B
    unsigned short* woT   = wqT + 576 * 192;             // 192*192 bf16 =  73728 B
    unsigned short* bias2 = woT + 192 * 192;             // 24576  bf16 =  49152 B (total 344064 B)

    to_bf16_T<<<dim3(9, 6), 256, 0, stream>>>(w_qkv, wqT, 192, 576);
    to_bf16_T<<<dim3(3, 6), 256, 0, stream>>>(w_out, woT, 192, 192);
    build_bias<<<dim3(96), 256, 0, stream>>>(rel_pos, bias2);

    wmsa_main<<<dim3(4 * NWIN), dim3(256), 0, stream>>>(
        x, b_qkv, bias2, b_out, wqT, woT, out);
}

// Round 4
// 318.591 us; speedup vs baseline: 15.8680x; 1.8568x over previous
//
#include <hip/hip_runtime.h>

typedef __attribute__((ext_vector_type(8))) short short8;
typedef __attribute__((ext_vector_type(4))) float f32x4;
typedef __attribute__((ext_vector_type(4))) unsigned short u16x4;

#define MFMA(a, b, c) __builtin_amdgcn_mfma_f32_16x16x32_bf16((a), (b), (c), 0, 0, 0)

namespace {
constexpr int IMG = 256;
constexpr int NWIN = 1024;
constexpr float SCALE = 0.17677669529663687f;  // 32^-0.5
}

__device__ __forceinline__ unsigned short f2bf(float f) {
    union { float f; unsigned u; } v; v.f = f;
    return (unsigned short)((v.u + 0x7FFFu + ((v.u >> 16) & 1u)) >> 16);
}
__device__ __forceinline__ float bf2f(unsigned short h) {
    union { unsigned u; float f; } v; v.u = ((unsigned)h) << 16;
    return v.f;
}
__device__ __forceinline__ unsigned pack2(float a, float b) {
    return (unsigned)f2bf(a) | ((unsigned)f2bf(b) << 16);
}

// fp32 [K][N] -> bf16 [N][K]
__global__ __launch_bounds__(256) void to_bf16_T(const float* __restrict__ in,
                                                 unsigned short* __restrict__ out,
                                                 int K, int N) {
    __shared__ float tile[32][65];
    const int t = threadIdx.x;
    const int nb = blockIdx.x * 64, kb = blockIdx.y * 32;
    const int tn = t & 63, tk = t >> 6;
#pragma unroll
    for (int p = 0; p < 8; ++p)
        tile[p * 4 + tk][tn] = in[(size_t)(kb + p * 4 + tk) * N + nb + tn];
    __syncthreads();
    const int n = t >> 2, kc = (t & 3) * 8;
    uint4 u;
    u.x = pack2(tile[kc + 0][n], tile[kc + 1][n]);
    u.y = pack2(tile[kc + 2][n], tile[kc + 3][n]);
    u.z = pack2(tile[kc + 4][n], tile[kc + 5][n]);
    u.w = pack2(tile[kc + 6][n], tile[kc + 7][n]);
    *(uint4*)(out + (size_t)(nb + n) * K + kb + kc) = u;
}

// bias2[((h*64+q)*16 + l15)*4 + nt] = rel_pos bias for (q, k=16*nt+l15), bf16
__global__ __launch_bounds__(256) void build_bias(const float* __restrict__ rel_pos,
                                                  unsigned short* __restrict__ bias2) {
    const int o = blockIdx.x * 256 + threadIdx.x;   // 0..24575
    const int nt = o & 3, l15 = (o >> 2) & 15, q = (o >> 6) & 63, h = o >> 12;
    const int k = 16 * nt + l15;
    const int qy = q >> 3, qx = q & 7, ky = k >> 3, kx = k & 7;
    bias2[o] = f2bf(rel_pos[h * 225 + (qy - ky + 7) * 15 + (qx - kx + 7)]);
}

__global__ __launch_bounds__(256, 2)
void wmsa_main(const float* __restrict__ x,
               const float* __restrict__ b_qkv,
               const unsigned short* __restrict__ bias2,
               const float* __restrict__ b_out,
               const unsigned short* __restrict__ wqT,   // bf16 [576][192]
               const unsigned short* __restrict__ woT,   // bf16 [192][192]
               float* __restrict__ out) {
    // strides are multiples of 8 halfwords so every frag read is ds_read_b128-aligned
    __shared__ unsigned short x_s[64][200];   // [tok][c]            25.6 KB
    __shared__ unsigned short qp_s[64][72];   // q(2 heads) / p(head0) 9.2 KB
    __shared__ unsigned short kp_s[64][72];   // k(2 heads) / p(head1) 9.2 KB
    __shared__ unsigned short vT_s[64][72];   // [d(2h*32)][tok]       9.2 KB
    __shared__ unsigned short oh_s[64][72];   // [tok][c(64)]          9.2 KB
    // total 62.4 KB -> 2 blocks/CU

    const int tid = threadIdx.x;
    const int w   = tid >> 6;
    const int l   = tid & 63;
    const int l15 = l & 15, lg = l >> 4;
    const int b   = blockIdx.x >> 10;
    const int win = blockIdx.x & (NWIN - 1);
    const int wy  = win >> 5, wx = win & 31;
    const bool lastwin = (win == NWIN - 1);
    const f32x4 z = {0.f, 0.f, 0.f, 0.f};

    // ---- stage x window -> bf16 LDS (roll(-4,-4) folded into pixel addr) ----
    for (int i = tid; i < 64 * 48; i += 256) {
        const int t = i / 48, c4 = i % 48;
        const int pr = ((wy << 3) + (t >> 3) + 4) & (IMG - 1);
        const int pc = ((wx << 3) + (t & 7) + 4) & (IMG - 1);
        const float4 xv = *reinterpret_cast<const float4*>(
            x + ((size_t)((b * IMG + pr) * IMG + pc)) * 192 + c4 * 4);
        uint2 pk; pk.x = pack2(xv.x, xv.y); pk.y = pack2(xv.z, xv.w);
        *(uint2*)(&x_s[t][c4 * 4]) = pk;
    }
    __syncthreads();

    const int h_loc = w >> 1;          // attention: head within group
    const int qt0   = 2 * (w & 1);     // attention: first q-tile

    f32x4 g2[3][4];                    // GEMM2 accumulators (persist across groups)
#pragma unroll
    for (int mi = 0; mi < 3; ++mi)
#pragma unroll
        for (int nt = 0; nt < 4; ++nt) g2[mi][nt] = z;

#pragma unroll 1
    for (int g = 0; g < 3; ++g) {      // head group: heads 2g, 2g+1
        // ==== phase 1: GEMM1, transposed D[col][tok]; wave owns col-tiles {w,w+4,w+8} ====
        f32x4 aq[3][4];
#pragma unroll
        for (int ci = 0; ci < 3; ++ci)
#pragma unroll
            for (int nt = 0; nt < 4; ++nt) aq[ci][nt] = z;

#pragma unroll
        for (int ks = 0; ks < 6; ++ks) {
            short8 xf[4];
#pragma unroll
            for (int nt = 0; nt < 4; ++nt)
                xf[nt] = *(const short8*)(&x_s[16 * nt + l15][ks * 32 + lg * 8]);
#pragma unroll
            for (int ci = 0; ci < 3; ++ci) {
                const int t = w + 4 * ci;                 // col-tile 0..11
                const int which = t >> 2, sub = t & 3;
                const int hh = sub >> 1, d0 = (sub & 1) * 16;
                const int grow = which * 192 + (2 * g + hh) * 32 + d0 + l15;
                const short8 wf = *(const short8*)(wqT + (size_t)grow * 192 + ks * 32 + lg * 8);
#pragma unroll
                for (int nt = 0; nt < 4; ++nt) aq[ci][nt] = MFMA(wf, xf[nt], aq[ci][nt]);
            }
        }
        // epilogue: lane holds col=tok(16nt+l15), rows = 4 consecutive cols d0+4lg+j
#pragma unroll
        for (int ci = 0; ci < 3; ++ci) {
            const int t = w + 4 * ci;
            const int which = t >> 2, sub = t & 3;
            const int hh = sub >> 1, d0 = (sub & 1) * 16;
            const int rbase = d0 + 4 * lg;                        // within head's 32
            const int bidx = which * 192 + (2 * g + hh) * 32 + rbase;
            const float b0 = b_qkv[bidx + 0], b1 = b_qkv[bidx + 1];
            const float b2 = b_qkv[bidx + 2], b3 = b_qkv[bidx + 3];
#pragma unroll
            for (int nt = 0; nt < 4; ++nt) {
                const int tok = 16 * nt + l15;
                float v0 = aq[ci][nt][0] + b0, v1 = aq[ci][nt][1] + b1;
                float v2 = aq[ci][nt][2] + b2, v3 = aq[ci][nt][3] + b3;
                if (which == 0) {
                    v0 *= SCALE; v1 *= SCALE; v2 *= SCALE; v3 *= SCALE;
                    uint2 pk; pk.x = pack2(v0, v1); pk.y = pack2(v2, v3);
                    *(uint2*)(&qp_s[tok][hh * 32 + rbase]) = pk;
                } else if (which == 1) {
                    uint2 pk; pk.x = pack2(v0, v1); pk.y = pack2(v2, v3);
                    *(uint2*)(&kp_s[tok][hh * 32 + rbase]) = pk;
                } else {
                    const int dr = hh * 32 + rbase;
                    vT_s[dr + 0][tok] = f2bf(v0);
                    vT_s[dr + 1][tok] = f2bf(v1);
                    vT_s[dr + 2][tok] = f2bf(v2);
                    vT_s[dr + 3][tok] = f2bf(v3);
                }
            }
        }
        __syncthreads();   // A: q/k/vT ready

        // ==== phase 2a: S = q k^T for this wave's half-head ====
        short8 qf[2], kf[4];
#pragma unroll
        for (int mq = 0; mq < 2; ++mq)
            qf[mq] = *(const short8*)(&qp_s[16 * (qt0 + mq) + l15][h_loc * 32 + lg * 8]);
#pragma unroll
        for (int nt = 0; nt < 4; ++nt)
            kf[nt] = *(const short8*)(&kp_s[16 * nt + l15][h_loc * 32 + lg * 8]);
        f32x4 s[2][4];
#pragma unroll
        for (int mq = 0; mq < 2; ++mq)
#pragma unroll
            for (int nt = 0; nt < 4; ++nt) s[mq][nt] = MFMA(qf[mq], kf[nt], z);
        __syncthreads();   // B: q/k buffers dead -> reuse as p

        // ==== phase 2b: softmax (no max-sub; |S+bias| bounded), p into aliased buf ====
        unsigned short (*p_buf)[72] = (h_loc == 0) ? qp_s : kp_s;
        const int h = 2 * g + h_loc;
#pragma unroll
        for (int mq = 0; mq < 2; ++mq) {
#pragma unroll
            for (int j = 0; j < 4; ++j) {
                const int q = 16 * (qt0 + mq) + 4 * lg + j;
                const u16x4 bb = *(const u16x4*)(bias2 + (((h * 64 + q) * 16 + l15) << 2));
                float e[4], sum = 0.f;
#pragma unroll
                for (int nt = 0; nt < 4; ++nt) {
                    float ee = __expf(s[mq][nt][j] + bf2f(bb[nt]));
                    if (lastwin && ((q < 4) != ((16 * nt + l15) < 4))) ee = 0.f;
                    e[nt] = ee; sum += ee;
                }
                sum += __shfl_xor(sum, 1);
                sum += __shfl_xor(sum, 2);
                sum += __shfl_xor(sum, 4);
                sum += __shfl_xor(sum, 8);
                const float ri = __builtin_amdgcn_rcpf(sum);
#pragma unroll
                for (int nt = 0; nt < 4; ++nt)
                    p_buf[q][16 * nt + l15] = f2bf(e[nt] * ri);
            }
        }

        // ==== phase 3: O^T = V^T P^T (reads own p rows; vT from phase 1) ====
        f32x4 o[2][2];
#pragma unroll
        for (int dm = 0; dm < 2; ++dm)
#pragma unroll
            for (int qn = 0; qn < 2; ++qn) o[dm][qn] = z;
#pragma unroll
        for (int ks2 = 0; ks2 < 2; ++ks2) {
            short8 pf[2];
#pragma unroll
            for (int qn = 0; qn < 2; ++qn)
                pf[qn] = *(const short8*)(&p_buf[16 * (qt0 + qn) + l15][ks2 * 32 + lg * 8]);
#pragma unroll
            for (int dm = 0; dm < 2; ++dm) {
                const short8 vf = *(const short8*)(&vT_s[h_loc * 32 + 16 * dm + l15][ks2 * 32 + lg * 8]);
#pragma unroll
                for (int qn = 0; qn < 2; ++qn) o[dm][qn] = MFMA(vf, pf[qn], o[dm][qn]);
            }
        }
#pragma unroll
        for (int dm = 0; dm < 2; ++dm)
#pragma unroll
            for (int qn = 0; qn < 2; ++qn) {
                const int tok = 16 * (qt0 + qn) + l15;
                const int c0 = h_loc * 32 + 16 * dm + 4 * lg;
                uint2 pk;
                pk.x = pack2(o[dm][qn][0], o[dm][qn][1]);
                pk.y = pack2(o[dm][qn][2], o[dm][qn][3]);
                *(uint2*)(&oh_s[tok][c0]) = pk;
            }
        __syncthreads();   // C: oh ready

        // ==== phase 4: GEMM2 partial, K-slice = this group's 64 channels ====
#pragma unroll
        for (int ks2 = 0; ks2 < 2; ++ks2) {
            short8 bfr[4];
#pragma unroll
            for (int nt = 0; nt < 4; ++nt)
                bfr[nt] = *(const short8*)(&oh_s[16 * nt + l15][ks2 * 32 + lg * 8]);
#pragma unroll
            for (int mi = 0; mi < 3; ++mi) {
                const int oct = w + 4 * mi;
                const short8 af = *(const short8*)(
                    woT + (size_t)(16 * oct + l15) * 192 + g * 64 + ks2 * 32 + lg * 8);
#pragma unroll
                for (int nt = 0; nt < 4; ++nt) g2[mi][nt] = MFMA(af, bfr[nt], g2[mi][nt]);
            }
        }
        // no barrier: next phase 1 writes qp/kp/vT (not read after C); oh_s is
        // overwritten only in next group's phase 3, i.e. after barriers A and B.
    }

    // ==== final store: D[oc][tok]; 12 float4 stores ====
#pragma unroll
    for (int nt = 0; nt < 4; ++nt) {
        const int tok = 16 * nt + l15;
        const int pr = ((wy << 3) + (tok >> 3) + 4) & (IMG - 1);
        const int pc = ((wx << 3) + (tok & 7) + 4) & (IMG - 1);
        float* orow = out + (size_t)((b * IMG + pr) * IMG + pc) * 192;
#pragma unroll
        for (int mi = 0; mi < 3; ++mi) {
            const int oc0 = 16 * (w + 4 * mi) + 4 * lg;
            const float4 bo = *reinterpret_cast<const float4*>(b_out + oc0);
            float4 vv;
            vv.x = g2[mi][nt][0] + bo.x; vv.y = g2[mi][nt][1] + bo.y;
            vv.z = g2[mi][nt][2] + bo.z; vv.w = g2[mi][nt][3] + bo.w;
            *reinterpret_cast<float4*>(orow + oc0) = vv;
        }
    }
}

extern "C" void kernel_launch(void* const* d_in, const int* in_sizes, int n_in,
                              void* d_out, int out_size, void* d_ws, size_t ws_size,
                              hipStream_t stream) {
    (void)in_sizes; (void)n_in; (void)out_size; (void)ws_size;
    const float* x       = (const float*)d_in[0];
    const float* w_qkv   = (const float*)d_in[1];
    const float* b_qkv   = (const float*)d_in[2];
    const float* rel_pos = (const float*)d_in[3];
    const float* w_out   = (const float*)d_in[4];
    const float* b_out   = (const float*)d_in[5];
    float* out = (float*)d_out;

    unsigned short* wqT   = (unsigned short*)d_ws;       // 576*192 bf16
    unsigned short* woT   = wqT + 576 * 192;             // 192*192 bf16
    unsigned short* bias2 = woT + 192 * 192;             // 24576 bf16 (total 344064 B)

    to_bf16_T<<<dim3(9, 6), 256, 0, stream>>>(w_qkv, wqT, 192, 576);
    to_bf16_T<<<dim3(3, 6), 256, 0, stream>>>(w_out, woT, 192, 192);
    build_bias<<<dim3(96), 256, 0, stream>>>(rel_pos, bias2);

    wmsa_main<<<dim3(4 * NWIN), dim3(256), 0, stream>>>(
        x, b_qkv, bias2, b_out, wqT, woT, out);
}